// Round 2
// baseline (1756.823 us; speedup 1.0000x reference)
//
#include <hip/hip_runtime.h>
#include <hip/hip_bf16.h>

#define NN 98
#define CC 192
#define NH 6
#define HDIM 32
#define NWIN 64
#define MPAD 100
#define NSTR 200   // O_lds row stride (bf16 elems)
#define SWS 1920   // per-wave staging elems (3840B)
#define NB 4096

// packed weight fragment array sizes (bf16 elems)
#define WKV_ELEMS 73728   // NH * 6ks * 4frag * 512
#define WQ_ELEMS  36864   // NH * 6ks * 2frag * 512
#define COMB_ELEMS (NWIN * NH * NN * MPAD)   // 3,763,200 floats
#define XT_ELEMS ((size_t)NB * 42 * 512)     // 88,080,384 bf16 (176 MB)

typedef float f32x4 __attribute__((ext_vector_type(4)));
typedef __bf16 bf16x8 __attribute__((ext_vector_type(8)));
typedef __bf16 bf16x4 __attribute__((ext_vector_type(4)));

__device__ __forceinline__ f32x4 mfma_bf16(bf16x8 a, bf16x8 b, f32x4 c) {
  return __builtin_amdgcn_mfma_f32_16x16x32_bf16(a, b, c, 0, 0, 0);
}

__device__ __forceinline__ bf16x8 zero8() {
  bf16x8 z;
#pragma unroll
  for (int i = 0; i < 8; ++i) z[i] = (__bf16)0.0f;
  return z;
}

__device__ __forceinline__ float fast_exp2(float x) {
#if __has_builtin(__builtin_amdgcn_exp2f)
  return __builtin_amdgcn_exp2f(x);
#else
  return exp2f(x);
#endif
}

// 8 contiguous fp32 from global -> bf16x8 fragment (fallback x path)
__device__ __forceinline__ bf16x8 ldw8(const float* __restrict__ p) {
  f32x4 a = *(const f32x4*)p;
  f32x4 b = *(const f32x4*)(p + 4);
  bf16x8 r;
  r[0] = (__bf16)a[0]; r[1] = (__bf16)a[1]; r[2] = (__bf16)a[2]; r[3] = (__bf16)a[3];
  r[4] = (__bf16)b[0]; r[5] = (__bf16)b[1]; r[6] = (__bf16)b[2]; r[7] = (__bf16)b[3];
  return r;
}

// O_lds A-fragment; rows >= 98 clamped (results discarded by n<NN store guard)
__device__ __forceinline__ bf16x8 ldo(const __bf16* p, int row, int k0) {
  int rc = row < NN ? row : (NN - 1);
  return *(const bf16x8*)(p + rc * NSTR + k0);
}

// comb = (bias + mask) * log2e, padded to stride 100 with -1e30.
// Weights packed in bf16 MFMA-fragment order (one coalesced 16B/lane load each).
__global__ void prep_small(const float* __restrict__ mask,
                           const float* __restrict__ rpb,
                           const int* __restrict__ rel_idx,
                           const float* __restrict__ qkv_w,
                           const float* __restrict__ proj_w,
                           float* __restrict__ comb,
                           __bf16* __restrict__ wkvp,
                           __bf16* __restrict__ wqp,
                           __bf16* __restrict__ wpp) {
  const float LOG2E = 1.4426950408889634f;
  int i = blockIdx.x * 256 + threadIdx.x;
  if (i < COMB_ELEMS) {
    int m = i % MPAD;
    int rem = i / MPAD;
    int n = rem % NN;
    int rem2 = rem / NN;
    int h = rem2 % NH;
    int wi = rem2 / NH;
    float v = -1e30f;
    if (m < NN)
      v = (rpb[rel_idx[n * NN + m] * NH + h] + mask[((size_t)wi * NN + n) * NN + m]) * LOG2E;
    comb[i] = v;
  }
  if (i < WKV_ELEMS) {
    // ((w*6+ks)*4+f)*512 + lane*8 + j ; f0,f1 = K cols 0/16 ; f2,f3 = V cols 0/16
    int j = i & 7;
    int lane = (i >> 3) & 63;
    int f = (i >> 9) & 3;
    int t = i >> 11;  // w*6 + ks
    int ks = t % 6;
    int w = t / 6;
    int l15 = lane & 15, quad = lane >> 4;
    int row = (f < 2 ? CC : 2 * CC) + w * HDIM + (f & 1) * 16 + l15;
    int col = ks * 32 + quad * 8 + j;
    wkvp[i] = (__bf16)qkv_w[row * CC + col];
  }
  if (i < WQ_ELEMS) {
    int j = i & 7;
    int lane = (i >> 3) & 63;
    int f = (i >> 9) & 1;
    int t = i >> 10;  // w*6 + ks
    int ks = t % 6;
    int w = t / 6;
    int l15 = lane & 15, quad = lane >> 4;
    int row = w * HDIM + f * 16 + l15;
    int col = ks * 32 + quad * 8 + j;
    wqp[i] = (__bf16)qkv_w[row * CC + col];
    wpp[i] = (__bf16)proj_w[row * CC + col];
  }
}

// Pre-tile x into bf16 MFMA A-fragment order: xt[((b*6+ks)*7+rt)*512 + lane*8 + j]
// = x[b][rt*16+l15][ks*32+quad*8+j], zero for rows >= 98.
__global__ void prep_x(const float* __restrict__ x, __bf16* __restrict__ xt) {
  int t = blockIdx.x * 256 + threadIdx.x;  // one thread per 8 elems
  int lane = t & 63;
  int fid = t >> 6;  // (b*6+ks)*7+rt
  int rt = fid % 7;
  int rem = fid / 7;
  int ks = rem % 6;
  int b = rem / 6;
  int l15 = lane & 15, quad = lane >> 4;
  int n = rt * 16 + l15;
  bf16x8 v;
  if (n < NN) {
    const float* p = x + ((size_t)b * NN + n) * CC + ks * 32 + quad * 8;
    v = ldw8(p);
  } else {
    v = zero8();
  }
  *(bf16x8*)&xt[(size_t)fid * 512 + lane * 8] = v;
}

// Barrier-free from launch through attention: x comes pre-tiled from global
// (no xs LDS, no staging barrier). Single __syncthreads() before out-proj
// (cross-head O exchange through O_lds).
template <bool XT>
__global__ __launch_bounds__(384, 3) void attn_kernel(
    const float* __restrict__ x,
    const float* __restrict__ qkv_b,
    const float* __restrict__ proj_b,
    const float* __restrict__ comb,
    const __bf16* __restrict__ wkvp,
    const __bf16* __restrict__ wqp,
    const __bf16* __restrict__ wpp,
    const __bf16* __restrict__ xt,
    float* __restrict__ out) {
  __shared__ alignas(16) __bf16 O_lds[NN * NSTR];   // 39200 B
  __shared__ alignas(16) __bf16 stage[NH * SWS];    // 23040 B per-wave private

  const int b = blockIdx.x;
  const int tid = threadIdx.x;
  const int w = tid >> 6;     // wave index == head index
  const int lane = tid & 63;
  const int l15 = lane & 15;
  const int quad = lane >> 4;
  __bf16* st = stage + w * SWS;
  const __bf16* xtb = xt + (size_t)b * (42 * 512);
  const float* xb = x + (size_t)b * (NN * CC);

  f32x4 acc[2][7];

  // ==== K pass ====
#pragma unroll
  for (int ct = 0; ct < 2; ++ct) {
    float bb = qkv_b[CC + w * HDIM + ct * 16 + l15];
#pragma unroll
    for (int rt = 0; rt < 7; ++rt) { f32x4 t = {bb, bb, bb, bb}; acc[ct][rt] = t; }
  }
  {
    const __bf16* wb = wkvp + (size_t)(w * 24) * 512 + lane * 8;
#pragma unroll
    for (int ks = 0; ks < 6; ++ks) {
      bf16x8 b0 = *(const bf16x8*)(wb + (ks * 4 + 0) * 512);
      bf16x8 b1 = *(const bf16x8*)(wb + (ks * 4 + 1) * 512);
#pragma unroll
      for (int rt = 0; rt < 7; ++rt) {
        bf16x8 a;
        if (XT) {
          a = *(const bf16x8*)&xtb[(ks * 7 + rt) * 512 + lane * 8];
        } else {
          int n = rt * 16 + l15;
          a = (n < NN) ? ldw8(xb + n * CC + ks * 32 + quad * 8) : zero8();
        }
        acc[0][rt] = mfma_bf16(a, b0, acc[0][rt]);
        acc[1][rt] = mfma_bf16(a, b1, acc[1][rt]);
      }
    }
  }

  // stage K tile-by-tile (wave-private [16][40]) -> A-frags ka[mt]
  bf16x8 ka[7];
#pragma unroll
  for (int rt = 0; rt < 7; ++rt) {
#pragma unroll
    for (int ct = 0; ct < 2; ++ct) {
      f32x4 v = acc[ct][rt];
      int hd = ct * 16 + l15;
#pragma unroll
      for (int r = 0; r < 4; ++r) st[(quad * 4 + r) * 40 + hd] = (__bf16)v[r];
    }
    ka[rt] = *(const bf16x8*)&st[l15 * 40 + quad * 8];  // rows>=98 finite garbage, masked via comb
  }

  // ==== V pass ====
#pragma unroll
  for (int ct = 0; ct < 2; ++ct) {
    float bb = qkv_b[2 * CC + w * HDIM + ct * 16 + l15];
#pragma unroll
    for (int rt = 0; rt < 7; ++rt) { f32x4 t = {bb, bb, bb, bb}; acc[ct][rt] = t; }
  }
  {
    const __bf16* wb = wkvp + (size_t)(w * 24) * 512 + lane * 8;
#pragma unroll
    for (int ks = 0; ks < 6; ++ks) {
      bf16x8 b0 = *(const bf16x8*)(wb + (ks * 4 + 2) * 512);
      bf16x8 b1 = *(const bf16x8*)(wb + (ks * 4 + 3) * 512);
#pragma unroll
      for (int rt = 0; rt < 7; ++rt) {
        bf16x8 a;
        if (XT) {
          a = *(const bf16x8*)&xtb[(ks * 7 + rt) * 512 + lane * 8];
        } else {
          int n = rt * 16 + l15;
          a = (n < NN) ? ldw8(xb + n * CC + ks * 32 + quad * 8) : zero8();
        }
        acc[0][rt] = mfma_bf16(a, b0, acc[0][rt]);
        acc[1][rt] = mfma_bf16(a, b1, acc[1][rt]);
      }
    }
  }

  // stage V in row-tile pairs (wave-private [32][40]) -> A-frags va[dt][ks]
  bf16x8 va[2][4];
#pragma unroll
  for (int ks = 0; ks < 4; ++ks) {
#pragma unroll
    for (int h2 = 0; h2 < 2; ++h2) {
      int rt = 2 * ks + h2;
      if (rt < 7) {
#pragma unroll
        for (int ct = 0; ct < 2; ++ct) {
          f32x4 v = acc[ct][rt];
          int d = ct * 16 + l15;
          int mloc = h2 * 16 + quad * 4;
          bf16x4 p;
#pragma unroll
          for (int r = 0; r < 4; ++r) p[r] = (__bf16)v[r];
          *(bf16x4*)&st[d * 40 + mloc] = p;
        }
      }
    }
#pragma unroll
    for (int dt = 0; dt < 2; ++dt) {
      bf16x8 f = *(const bf16x8*)&st[(dt * 16 + l15) * 40 + quad * 8];
      if (ks == 3 && quad >= 2) f = zero8();  // m >= 112 (unwritten region)
      va[dt][ks] = f;
    }
  }

  // ==== Q pass ====
#pragma unroll
  for (int ct = 0; ct < 2; ++ct) {
    float bq = qkv_b[w * HDIM + ct * 16 + l15];
#pragma unroll
    for (int rt = 0; rt < 7; ++rt) { f32x4 t = {bq, bq, bq, bq}; acc[ct][rt] = t; }
  }
  {
    const __bf16* wb = wqp + (size_t)(w * 12) * 512 + lane * 8;
#pragma unroll
    for (int ks = 0; ks < 6; ++ks) {
      bf16x8 b0 = *(const bf16x8*)(wb + (ks * 2 + 0) * 512);
      bf16x8 b1 = *(const bf16x8*)(wb + (ks * 2 + 1) * 512);
#pragma unroll
      for (int rt = 0; rt < 7; ++rt) {
        bf16x8 a;
        if (XT) {
          a = *(const bf16x8*)&xtb[(ks * 7 + rt) * 512 + lane * 8];
        } else {
          int n = rt * 16 + l15;
          a = (n < NN) ? ldw8(xb + n * CC + ks * 32 + quad * 8) : zero8();
        }
        acc[0][rt] = mfma_bf16(a, b0, acc[0][rt]);
        acc[1][rt] = mfma_bf16(a, b1, acc[1][rt]);
      }
    }
  }

  // stage Q (scale * log2e folded) tile-by-tile -> B-frags qb[nb]
  const float qscale = 0.17677669529663687f * 1.4426950408889634f;
  bf16x8 qb[7];
#pragma unroll
  for (int rt = 0; rt < 7; ++rt) {
#pragma unroll
    for (int ct = 0; ct < 2; ++ct) {
      f32x4 v = acc[ct][rt];
      int hd = ct * 16 + l15;
#pragma unroll
      for (int r = 0; r < 4; ++r) st[(quad * 4 + r) * 40 + hd] = (__bf16)(v[r] * qscale);
    }
    qb[rt] = *(const bf16x8*)&st[l15 * 40 + quad * 8];  // cols>=98 garbage, never stored
  }

  // ---- attention (no barrier needed before this: O_lds untouched so far) ----
  const int wmask = b & (NWIN - 1);
  const float* cbase = comb + (size_t)(wmask * NH + w) * NN * MPAD;
#pragma unroll 1
  for (int nb = 0; nb < 7; ++nb) {
    const f32x4 z4 = {0.f, 0.f, 0.f, 0.f};
    const f32x4 neg4 = {-1e30f, -1e30f, -1e30f, -1e30f};

    int n = nb * 16 + l15;
    bool nvalid = (n < NN);
    int nc = nvalid ? n : 0;
    const float* cp = cbase + (size_t)nc * MPAD;

    // prefetch all bias+mask lines first so their latency overlaps the MFMAs
    f32x4 addv[7];
#pragma unroll
    for (int mt = 0; mt < 7; ++mt) {
      int m0 = mt * 16 + quad * 4;
      addv[mt] = (m0 < MPAD) ? *(const f32x4*)(cp + m0) : neg4;
    }

    f32x4 sacc[7];
#pragma unroll
    for (int mt = 0; mt < 7; ++mt) sacc[mt] = mfma_bf16(ka[mt], qb[nb], z4);

    float mx = -3.0e38f;
#pragma unroll
    for (int mt = 0; mt < 7; ++mt) {
#pragma unroll
      for (int r = 0; r < 4; ++r) {
        float v = sacc[mt][r] + addv[mt][r];  // -1e30 padding dominates invalid m
        sacc[mt][r] = v;
        mx = fmaxf(mx, v);
      }
    }
    mx = fmaxf(mx, __shfl_xor(mx, 16, 64));
    mx = fmaxf(mx, __shfl_xor(mx, 32, 64));
    float sum = 0.f;
#pragma unroll
    for (int mt = 0; mt < 7; ++mt) {
#pragma unroll
      for (int r = 0; r < 4; ++r) {
        float p = fast_exp2(sacc[mt][r] - mx);
        sacc[mt][r] = p;
        sum += p;
      }
    }
    sum += __shfl_xor(sum, 16, 64);
    sum += __shfl_xor(sum, 32, 64);
    float rinv = 1.0f / sum;

    // write P to wave-private [16][120] LDS, reload as B-frags
#pragma unroll
    for (int mt = 0; mt < 7; ++mt) {
      bf16x4 p;
#pragma unroll
      for (int r = 0; r < 4; ++r) p[r] = (__bf16)sacc[mt][r];
      *(bf16x4*)&st[l15 * 120 + mt * 16 + quad * 4] = p;
    }
    bf16x8 pf[4];
#pragma unroll
    for (int ks = 0; ks < 4; ++ks) {
      bf16x8 f = *(const bf16x8*)&st[l15 * 120 + ks * 32 + quad * 8];
      if (ks == 3 && quad >= 2) f = zero8();
      pf[ks] = f;
    }

#pragma unroll
    for (int dt = 0; dt < 2; ++dt) {
      f32x4 o = z4;
#pragma unroll
      for (int ks = 0; ks < 4; ++ks) o = mfma_bf16(va[dt][ks], pf[ks], o);
      if (nvalid) {
        bf16x4 p;
#pragma unroll
        for (int r = 0; r < 4; ++r) p[r] = (__bf16)(o[r] * rinv);
        *(bf16x4*)&O_lds[n * NSTR + w * HDIM + dt * 16 + quad * 4] = p;
      }
    }
  }
  __syncthreads();  // O_lds complete (the ONLY barrier)

  // ---- output projection: out = O @ proj_w^T + proj_b ----
  f32x4 accP[2][7];
#pragma unroll
  for (int ct = 0; ct < 2; ++ct) {
    float pb = proj_b[w * HDIM + ct * 16 + l15];
#pragma unroll
    for (int rt = 0; rt < 7; ++rt) { f32x4 t = {pb, pb, pb, pb}; accP[ct][rt] = t; }
  }
  {
    const __bf16* wb = wpp + (size_t)(w * 12) * 512 + lane * 8;
#pragma unroll
    for (int ks = 0; ks < 6; ++ks) {
      bf16x8 b0 = *(const bf16x8*)(wb + (ks * 2 + 0) * 512);
      bf16x8 b1 = *(const bf16x8*)(wb + (ks * 2 + 1) * 512);
      const int k0 = ks * 32 + quad * 8;
#pragma unroll
      for (int rt = 0; rt < 7; ++rt) {
        bf16x8 a = ldo(O_lds, rt * 16 + l15, k0);
        accP[0][rt] = mfma_bf16(a, b0, accP[0][rt]);
        accP[1][rt] = mfma_bf16(a, b1, accP[1][rt]);
      }
    }
  }

  // paired stores: ct0+ct1 adjacent -> each 128B line written contiguously
  float* ob = out + (size_t)b * (NN * CC);
  const int c0 = w * HDIM + l15;
#pragma unroll
  for (int rt = 0; rt < 7; ++rt) {
#pragma unroll
    for (int r = 0; r < 4; ++r) {
      int n = rt * 16 + quad * 4 + r;
      if (n < NN) {
        ob[n * CC + c0] = accP[0][rt][r];
        ob[n * CC + c0 + 16] = accP[1][rt][r];
      }
    }
  }
}

extern "C" void kernel_launch(void* const* d_in, const int* in_sizes, int n_in,
                              void* d_out, int out_size, void* d_ws, size_t ws_size,
                              hipStream_t stream) {
  const float* x = (const float*)d_in[0];
  const float* mask = (const float*)d_in[1];
  const float* qkv_w = (const float*)d_in[2];
  const float* qkv_b = (const float*)d_in[3];
  const float* proj_w = (const float*)d_in[4];
  const float* proj_b = (const float*)d_in[5];
  const float* rpb = (const float*)d_in[6];
  const int* rel_idx = (const int*)d_in[7];

  float* comb = (float*)d_ws;                          // 15.05 MB
  __bf16* wkvp = (__bf16*)(comb + COMB_ELEMS);
  __bf16* wqp = wkvp + WKV_ELEMS;
  __bf16* wpp = wqp + WQ_ELEMS;
  __bf16* xt = wpp + WQ_ELEMS;                         // 176.2 MB

  size_t needed = (size_t)COMB_ELEMS * 4 +
                  (size_t)(WKV_ELEMS + 2 * WQ_ELEMS) * 2 +
                  XT_ELEMS * 2;
  bool use_xt = ws_size >= needed;

  prep_small<<<(COMB_ELEMS + 255) / 256, 256, 0, stream>>>(
      mask, rpb, rel_idx, qkv_w, proj_w, comb, wkvp, wqp, wpp);
  if (use_xt) {
    prep_x<<<(int)((XT_ELEMS / 8) / 256), 256, 0, stream>>>(x, xt);
    attn_kernel<true><<<NB, 384, 0, stream>>>(x, qkv_b, proj_b, comb,
                                              wkvp, wqp, wpp, xt, (float*)d_out);
  } else {
    attn_kernel<false><<<NB, 384, 0, stream>>>(x, qkv_b, proj_b, comb,
                                               wkvp, wqp, wpp, xt, (float*)d_out);
  }
}